// Round 2
// baseline (11112.659 us; speedup 1.0000x reference)
//
#include <hip/hip_runtime.h>
#include <stdint.h>

// ---------- types / helpers ----------
typedef __attribute__((ext_vector_type(8))) short short8;   // 8 bf16 in 4 VGPRs
typedef __attribute__((ext_vector_type(4))) float f32x4;

__device__ __forceinline__ unsigned short f32_to_bf16(float f) {
    unsigned int u = __float_as_uint(f);
    unsigned int r = (u + 0x7FFF + ((u >> 16) & 1)) >> 16;   // RNE
    return (unsigned short)r;
}
__device__ __forceinline__ float bf16_to_f32(unsigned short s) {
    return __uint_as_float(((unsigned int)s) << 16);
}

// ---------- prep kernels ----------
__global__ void cvt_bf16_kernel(const float* __restrict__ in,
                                unsigned short* __restrict__ out, int n) {
    int i = (blockIdx.x * blockDim.x + threadIdx.x) * 4;
    if (i >= n) return;
    float4 v = *(const float4*)(in + i);
    ushort4 o;
    o.x = f32_to_bf16(v.x);
    o.y = f32_to_bf16(v.y);
    o.z = f32_to_bf16(v.z);
    o.w = f32_to_bf16(v.w);
    *(ushort4*)(out + i) = o;
}

__global__ void bias_add_kernel(const float* __restrict__ bi,
                                const float* __restrict__ bh,
                                float* __restrict__ bias) {
    int i = blockIdx.x * blockDim.x + threadIdx.x;  // 4096
    bias[i] = bi[i] + bh[i];
}

// h0,c0 are [b][j]; state buffers transposed [j][b]. h in bf16, c in fp32.
__global__ void init_state_kernel(const float* __restrict__ h0,
                                  const float* __restrict__ c0,
                                  unsigned short* __restrict__ hbuf,
                                  float* __restrict__ cbuf) {
    int i = blockIdx.x * blockDim.x + threadIdx.x;  // 32768
    int b = i >> 10, j = i & 1023;
    hbuf[j * 32 + b] = f32_to_bf16(h0[i]);
    cbuf[j * 32 + b] = c0[i];
}

// ---------- phase 1: xg[r][g] = bf16( A[r][:]·B[g][:] + bias[g] ), r=b*512+t ----------
#define BM 64
#define BN 64
#define LDP 40  // padded LDS row pitch (shorts): 2-way conflicts only (free)

__global__ __launch_bounds__(256) void gemm_xproj(
    const unsigned short* __restrict__ A,   // x bf16 [16384][1024]
    const unsigned short* __restrict__ B,   // W_ih bf16 [4096][1024]
    const float* __restrict__ bias,         // [4096]
    unsigned short* __restrict__ C) {       // xg bf16 [16384][4096]
    __shared__ unsigned short As[BM][LDP];
    __shared__ unsigned short Bs[BN][LDP];
    const int tid  = threadIdx.x;
    const int lane = tid & 63;
    const int wave = tid >> 6;
    const int m0 = blockIdx.y * BM;
    const int n0 = blockIdx.x * BN;
    const int wm = (wave & 1) * 32;
    const int wn = (wave >> 1) * 32;

    f32x4 acc[2][2] = {};

    const int sr = tid >> 2;       // staging row 0..63
    const int sk = (tid & 3) * 8;  // staging k-seg (8 bf16 = 16B)
    const int fr = lane & 15;
    const int fk = (lane >> 4) * 8;

    for (int k0 = 0; k0 < 1024; k0 += 32) {
        uint4 av = *(const uint4*)&A[(m0 + sr) * 1024 + k0 + sk];
        uint4 bv = *(const uint4*)&B[(n0 + sr) * 1024 + k0 + sk];
        __syncthreads();
        *(uint4*)&As[sr][sk] = av;
        *(uint4*)&Bs[sr][sk] = bv;
        __syncthreads();
        short8 a0 = *(const short8*)&As[wm + fr][fk];
        short8 a1 = *(const short8*)&As[wm + 16 + fr][fk];
        short8 b0 = *(const short8*)&Bs[wn + fr][fk];
        short8 b1 = *(const short8*)&Bs[wn + 16 + fr][fk];
        acc[0][0] = __builtin_amdgcn_mfma_f32_16x16x32_bf16(a0, b0, acc[0][0], 0, 0, 0);
        acc[0][1] = __builtin_amdgcn_mfma_f32_16x16x32_bf16(a0, b1, acc[0][1], 0, 0, 0);
        acc[1][0] = __builtin_amdgcn_mfma_f32_16x16x32_bf16(a1, b0, acc[1][0], 0, 0, 0);
        acc[1][1] = __builtin_amdgcn_mfma_f32_16x16x32_bf16(a1, b1, acc[1][1], 0, 0, 0);
    }

    // C/D layout (verified m89/m91): col = lane&15, row = (lane>>4)*4 + r
    const int col = lane & 15;
    const int rq  = (lane >> 4) * 4;
    for (int mt = 0; mt < 2; mt++) {
        for (int nt = 0; nt < 2; nt++) {
            int gcol = n0 + wn + nt * 16 + col;
            float bv = bias[gcol];
            for (int r = 0; r < 4; r++) {
                int grow = m0 + wm + mt * 16 + rq + r;
                C[(size_t)grow * 4096 + gcol] = f32_to_bf16(acc[mt][nt][r] + bv);
            }
        }
    }
}

// ---------- phase 2: one timestep ----------
// 256 blocks x 512 threads. Block covers 4 hidden j, all 4 gates, all 32 batches.
// tid = kh*128 + j*32 + b, kh = 4-way k split (k-slice of 256).
// h state transposed bf16 [1024][32]; c fp32 [1024][32] (block-owned, never crosses).
// USE_XG: fast path (xg precomputed, bias folded). !USE_XG: fused fallback,
// recomputes x-projection from raw fp32 x and W_ih (ws too small for xg).
template <bool USE_XG>
__global__ __launch_bounds__(512) void lstm_step(
    const float* __restrict__ Whh,          // [4096][1024] fp32
    const float* __restrict__ Wih,          // fallback only
    const float* __restrict__ x,            // fallback only: [32][512][1024] fp32
    const unsigned short* __restrict__ xg,  // fast only: bf16 [16384][4096]
    const float* __restrict__ bias,         // fallback only
    const unsigned short* __restrict__ h_in,
    unsigned short* __restrict__ h_out,
    float* __restrict__ c,
    float* __restrict__ out,                // d_out fp32 [32][1024], written every step
    int t) {
    __shared__ float part[4 * 4 * 4 * 32];  // [kh][q][j][b] = 8 KB
    const int tid = threadIdx.x;
    const int b  = tid & 31;
    const int jt = (tid >> 5) & 3;
    const int kh = tid >> 7;
    const int j0 = blockIdx.x * 4;
    const int kbase = kh * 256;

    // prefetch per-(j,b) gate inputs early (tail threads only; kh==0 there)
    float xz[4] = {0.f, 0.f, 0.f, 0.f};
    if (tid < 128) {
        if (USE_XG) {
            const unsigned short* p = xg + (size_t)(b * 512 + t) * 4096 + j0 + jt;
#pragma unroll
            for (int q = 0; q < 4; q++) xz[q] = bf16_to_f32(p[q * 1024]);
        } else {
#pragma unroll
            for (int q = 0; q < 4; q++) xz[q] = bias[q * 1024 + j0 + jt];
        }
    }

    const unsigned short* hp = h_in + kbase * 32 + b;
    const float* w0 = Whh + (size_t)(j0 + jt) * 1024 + kbase;

    float a0 = 0.f, a1 = 0.f, a2 = 0.f, a3 = 0.f;
#pragma unroll 2
    for (int k = 0; k < 256; k += 4) {
        float4 wa = *(const float4*)(w0 + k);
        float4 wb = *(const float4*)(w0 + 1048576 + k);
        float4 wc = *(const float4*)(w0 + 2097152 + k);
        float4 wd = *(const float4*)(w0 + 3145728 + k);
        float h0v = bf16_to_f32(hp[(k + 0) * 32]);
        float h1v = bf16_to_f32(hp[(k + 1) * 32]);
        float h2v = bf16_to_f32(hp[(k + 2) * 32]);
        float h3v = bf16_to_f32(hp[(k + 3) * 32]);
        a0 += wa.x * h0v + wa.y * h1v + wa.z * h2v + wa.w * h3v;
        a1 += wb.x * h0v + wb.y * h1v + wb.z * h2v + wb.w * h3v;
        a2 += wc.x * h0v + wc.y * h1v + wc.z * h2v + wc.w * h3v;
        a3 += wd.x * h0v + wd.y * h1v + wd.z * h2v + wd.w * h3v;
    }

    if (!USE_XG) {
        // fused x-projection: per-thread contiguous fp32 x slice
        const float* xrow = x + (size_t)(b * 512 + t) * 1024 + kbase;
        const float* u0 = Wih + (size_t)(j0 + jt) * 1024 + kbase;
#pragma unroll 2
        for (int k = 0; k < 256; k += 4) {
            float4 xv = *(const float4*)(xrow + k);
            float4 wa = *(const float4*)(u0 + k);
            float4 wb = *(const float4*)(u0 + 1048576 + k);
            float4 wc = *(const float4*)(u0 + 2097152 + k);
            float4 wd = *(const float4*)(u0 + 3145728 + k);
            a0 += wa.x * xv.x + wa.y * xv.y + wa.z * xv.z + wa.w * xv.w;
            a1 += wb.x * xv.x + wb.y * xv.y + wb.z * xv.z + wb.w * xv.w;
            a2 += wc.x * xv.x + wc.y * xv.y + wc.z * xv.z + wc.w * xv.w;
            a3 += wd.x * xv.x + wd.y * xv.y + wd.z * xv.z + wd.w * xv.w;
        }
    }

    part[((kh * 4 + 0) * 4 + jt) * 32 + b] = a0;
    part[((kh * 4 + 1) * 4 + jt) * 32 + b] = a1;
    part[((kh * 4 + 2) * 4 + jt) * 32 + b] = a2;
    part[((kh * 4 + 3) * 4 + jt) * 32 + b] = a3;
    __syncthreads();

    if (tid < 128) {  // (jt, b) tail
        float z[4];
#pragma unroll
        for (int q = 0; q < 4; q++) {
            float s = xz[q];
#pragma unroll
            for (int kk = 0; kk < 4; kk++) s += part[((kk * 4 + q) * 4 + jt) * 32 + b];
            z[q] = s;
        }
        float ig = 1.f / (1.f + __expf(-z[0]));
        float fg = 1.f / (1.f + __expf(-z[1]));
        float gg = tanhf(z[2]);
        float og = 1.f / (1.f + __expf(-z[3]));
        int idx = (j0 + jt) * 32 + b;
        float cn = fg * c[idx] + ig * gg;
        c[idx] = cn;
        float hn = og * tanhf(cn);
        h_out[idx] = f32_to_bf16(hn);
        out[b * 1024 + j0 + jt] = hn;  // fp32 final output, overwritten each step
    }
}

// ---------- launch ----------
extern "C" void kernel_launch(void* const* d_in, const int* in_sizes, int n_in,
                              void* d_out, int out_size, void* d_ws, size_t ws_size,
                              hipStream_t stream) {
    const float* x    = (const float*)d_in[0];  // [32][512][1024]
    const float* h0   = (const float*)d_in[1];  // [32][1024]
    const float* c0   = (const float*)d_in[2];  // [32][1024]
    const float* Wih  = (const float*)d_in[3];  // [4096][1024]
    const float* Whh  = (const float*)d_in[4];  // [4096][1024]
    const float* b_ih = (const float*)d_in[5];  // [4096]
    const float* b_hh = (const float*)d_in[6];  // [4096]
    float* out = (float*)d_out;
    char* ws = (char*)d_ws;

    // fast-path workspace layout (168.3 MB total)
    const size_t OFF_XG   = 0;            // bf16 xg   134217728 B
    const size_t OFF_XA   = 134217728;    // bf16 x     33554432 B
    const size_t OFF_WB   = 167772160;    // bf16 W_ih   8388608 B
    const size_t OFF_BIAS = 176160768;    // f32 bias      16384 B
    const size_t OFF_HA   = 176177152;    // bf16 hA       65536 B
    const size_t OFF_HB   = 176242688;    // bf16 hB       65536 B
    const size_t OFF_CB   = 176308224;    // f32 c        131072 B
    const size_t WS_FAST  = 176439296;

    const bool fast = (ws_size >= WS_FAST);

    if (fast) {
        unsigned short* xg   = (unsigned short*)(ws + OFF_XG);
        unsigned short* xA   = (unsigned short*)(ws + OFF_XA);
        unsigned short* wB   = (unsigned short*)(ws + OFF_WB);
        float*          bias = (float*)(ws + OFF_BIAS);
        unsigned short* hA   = (unsigned short*)(ws + OFF_HA);
        unsigned short* hB   = (unsigned short*)(ws + OFF_HB);
        float*          cb   = (float*)(ws + OFF_CB);

        cvt_bf16_kernel<<<16777216 / 4 / 256, 256, 0, stream>>>(x, xA, 16777216);
        cvt_bf16_kernel<<<4194304 / 4 / 256, 256, 0, stream>>>(Wih, wB, 4194304);
        bias_add_kernel<<<16, 256, 0, stream>>>(b_ih, b_hh, bias);
        init_state_kernel<<<128, 256, 0, stream>>>(h0, c0, hA, cb);

        dim3 g1(64, 256);
        gemm_xproj<<<g1, 256, 0, stream>>>(xA, wB, bias, xg);

        for (int t = 0; t < 512; t++) {
            const unsigned short* hi = (t & 1) ? hB : hA;
            unsigned short*       ho = (t & 1) ? hA : hB;
            lstm_step<true><<<256, 512, 0, stream>>>(Whh, nullptr, nullptr, xg,
                                                     nullptr, hi, ho, cb, out, t);
        }
    } else {
        // minimal-workspace fallback (280 KB): fused x-projection per step
        float*          bias = (float*)(ws + 0);
        unsigned short* hA   = (unsigned short*)(ws + 16384);
        unsigned short* hB   = (unsigned short*)(ws + 81920);
        float*          cb   = (float*)(ws + 147456);

        bias_add_kernel<<<16, 256, 0, stream>>>(b_ih, b_hh, bias);
        init_state_kernel<<<128, 256, 0, stream>>>(h0, c0, hA, cb);

        for (int t = 0; t < 512; t++) {
            const unsigned short* hi = (t & 1) ? hB : hA;
            unsigned short*       ho = (t & 1) ? hA : hB;
            lstm_step<false><<<256, 512, 0, stream>>>(Whh, Wih, x, nullptr,
                                                      bias, hi, ho, cb, out, t);
        }
    }
}